// Round 11
// baseline (116.390 us; speedup 1.0000x reference)
//
#include <hip/hip_runtime.h>
#include <hip/hip_bf16.h>

// Problem constants
#define B_   4
#define C_   32
#define H_   192
#define W_   192
#define HW_  (H_ * W_)          // 36864
#define EPS_ 1e-5f

#define SCALE_IN  21.640425613334453f   // beta/ln2
#define SCALE_OUT 0.046209812037329687f // ln2/beta

// LDS strides chosen so stride mod 32 has additive order 8 (gcd(s,32)=4):
// consecutive rows start at distinct bank phases -> no systematic conflicts.
// Both are multiples of 4 floats -> float4 (16B) alignment preserved.
#define SPW 52                  // sP row stride (rows: 48)
#define SQW 44                  // sQ row stride (rows: 40)

#define NP1 (128 * 576)         // chan * (4 b * 36 tiles * 4 waves)
#define NP2 (32 * 4 * 144)

// bf16 <-> f32 helpers (bit-exact shift load, RNE store)
__device__ __forceinline__ float bf2f(unsigned short u) {
    return __uint_as_float((unsigned int)u << 16);
}
__device__ __forceinline__ unsigned short f2bf(float f) {
    const unsigned int u = __float_as_uint(f);
    return (unsigned short)((u + 0x7fffu + ((u >> 16) & 1u)) >> 16);
}

// ---------------------------------------------------------------------------
// Scratch (module globals; no atomics anywhere).
// ---------------------------------------------------------------------------
__device__ float          g_cw[2304];
__device__ float          g_Wt[4096];
__device__ float          g_stats[320];
__device__ float          g_p1[2 * NP1];
__device__ float          g_p2[2 * NP2];
__device__ __attribute__((aligned(16))) unsigned short g_E[(size_t)4 * B_ * C_ * HW_]; // 37.75 MB
__device__ __attribute__((aligned(16))) float          g_Y[(size_t)B_ * C_ * HW_];     // 18.87 MB

// ---------------------------------------------------------------------------
// prep: exponentiate morphology weights + transpose conv weights
// ---------------------------------------------------------------------------
__global__ void prep_k(const float* __restrict__ wd, const float* __restrict__ we,
                       const float* __restrict__ Wc) {
    for (int i = threadIdx.x; i < 2304; i += 256) {
        const float v = (i < 1152) ? wd[i] : we[i - 1152];
        g_cw[i] = exp2f(SCALE_IN * v);
    }
    for (int i = threadIdx.x; i < 4096; i += 256) {
        const int ci = i >> 5;
        const int k  = i & 31;
        g_Wt[i] = Wc[(size_t)k * 128 + ci];
    }
}

// ---------------------------------------------------------------------------
// One morphology branch (dilate-recip + erode) on a staged 48-row P tile.
// sP: P = 2^(s*x), halo +-8, out-of-image = 1.0 (zero-pad), stride SPW.
// sQ: Q = 1/dilate-sum, stride SQW.
// All tap/window indices compile-time via D. 4 cells per thread, f4 LDS ops.
// ---------------------------------------------------------------------------
template<int D>
__device__ __forceinline__ void morph_branch(int b, int c, int h0, int w0,
                                             int slotbase,
                                             const float* __restrict__ sP,
                                             float* __restrict__ sQ) {
    constexpr int QE   = 32 + 2 * D;          // Q extent needed by this branch
    constexpr int QEG  = (QE + 3) / 4;        // float4 groups per Q row
    constexpr int UNITS = QE * QEG;           // <= 400
    constexpr int POFF = 8 - 2 * D;           // window start col offset in sP
    constexpr int AB   = POFF & ~3;           // aligned base
    constexpr int OFF  = POFF & 3;            // start within reg buffer
    constexpr int NR   = (OFF + 2 * D + 4 + 3) / 4;  // f4 reads/row (phase 2)
    constexpr int NR3  = (2 * D + 4 + 3) / 4;        // f4 reads/row (phase 3)
    constexpr int br   = D - 1;

    const int tid = threadIdx.x;
    const int cb  = (br * C_ + c) * 9;

    // ---- phase 2: Q = rcp( sum cd * P_taps ); out-of-image cells := 1 ----
    {
        float cd[9];
#pragma unroll
        for (int k = 0; k < 9; k++) cd[k] = g_cw[cb + k];

#pragma unroll
        for (int it = 0; it < 2; ++it) {
            const int unit = tid + it * 256;
            if (unit < UNITS) {
                const int qi = unit / QEG;                 // compile-time magic div
                const int qj = (unit - qi * QEG) * 4;
                float a0 = 0.f, a1 = 0.f, a2 = 0.f, a3 = 0.f;
#pragma unroll
                for (int i = 0; i < 3; i++) {
                    const float* rp = &sP[(qi + 8 + (i - 2) * D) * SPW + qj + AB];
                    float buf[NR * 4];
#pragma unroll
                    for (int r = 0; r < NR; r++)
                        *(float4*)&buf[r * 4] = *(const float4*)&rp[r * 4];
#pragma unroll
                    for (int j = 0; j < 3; j++) {
                        const float wgt = cd[i * 3 + j];
                        a0 = fmaf(wgt, buf[OFF + j * D + 0], a0);
                        a1 = fmaf(wgt, buf[OFF + j * D + 1], a1);
                        a2 = fmaf(wgt, buf[OFF + j * D + 2], a2);
                        a3 = fmaf(wgt, buf[OFF + j * D + 3], a3);
                    }
                }
                float q0 = __builtin_amdgcn_rcpf(a0);
                float q1 = __builtin_amdgcn_rcpf(a1);
                float q2 = __builtin_amdgcn_rcpf(a2);
                float q3 = __builtin_amdgcn_rcpf(a3);
                const int hq = h0 - D + qi;
                const int wq = w0 - D + qj;
                const bool rowo = (hq < 0) || (hq >= H_);
                q0 = (rowo || (wq + 0 < 0) || (wq + 0 >= W_)) ? 1.0f : q0;
                q1 = (rowo || (wq + 1 < 0) || (wq + 1 >= W_)) ? 1.0f : q1;
                q2 = (rowo || (wq + 2 < 0) || (wq + 2 >= W_)) ? 1.0f : q2;
                q3 = (rowo || (wq + 3 < 0) || (wq + 3 >= W_)) ? 1.0f : q3;
                *(float4*)&sQ[qi * SQW + qj] = make_float4(q0, q1, q2, q3);
            }
        }
    }
    __syncthreads();

    // ---- phase 3: E = -(ln2/beta)*log2( sum ce * Q_taps ), 4 px/thread ----
    {
        float ce[9];
#pragma unroll
        for (int k = 0; k < 9; k++) ce[k] = g_cw[1152 + cb + k];

        const int oi = tid >> 3;
        const int oj = (tid & 7) * 4;
        float t0 = 0.f, t1 = 0.f, t2 = 0.f, t3 = 0.f;
#pragma unroll
        for (int i = 0; i < 3; i++) {
            const float* rq = &sQ[(oi + i * D) * SQW + oj];
            float buf[NR3 * 4];
#pragma unroll
            for (int r = 0; r < NR3; r++)
                *(float4*)&buf[r * 4] = *(const float4*)&rq[r * 4];
#pragma unroll
            for (int j = 0; j < 3; j++) {
                const float wgt = ce[i * 3 + j];
                t0 = fmaf(wgt, buf[j * D + 0], t0);
                t1 = fmaf(wgt, buf[j * D + 1], t1);
                t2 = fmaf(wgt, buf[j * D + 2], t2);
                t3 = fmaf(wgt, buf[j * D + 3], t3);
            }
        }
        const float e0 = -SCALE_OUT * log2f(t0);
        const float e1 = -SCALE_OUT * log2f(t1);
        const float e2 = -SCALE_OUT * log2f(t2);
        const float e3 = -SCALE_OUT * log2f(t3);

        ushort4 r4;
        r4.x = f2bf(e0); r4.y = f2bf(e1); r4.z = f2bf(e2); r4.w = f2bf(e3);
        *(ushort4*)&g_E[(((size_t)br * B_ + b) * C_ + c) * HW_
                        + (size_t)(h0 + oi) * W_ + w0 + oj] = r4;

        // per-wave BN1 partials straight to private global slots
        float s1 = e0 + e1 + e2 + e3;
        float s2 = e0 * e0 + e1 * e1 + e2 * e2 + e3 * e3;
#pragma unroll
        for (int off = 32; off >= 1; off >>= 1) {
            s1 += __shfl_down(s1, off, 64);
            s2 += __shfl_down(s2, off, 64);
        }
        if ((tid & 63) == 0) {
            const int slot = (br * C_ + c) * 576 + slotbase + (tid >> 6);
            g_p1[slot]       = s1;
            g_p1[NP1 + slot] = s2;
        }
    }
    __syncthreads();   // protect sQ before next branch's phase 2
}

// ---------------------------------------------------------------------------
// fused all-branch morphology. grid (36 tiles, 32 c, 4 b), 256 threads.
// Stages P once (from x, halo 8, pad 1.0), runs branches D=1..4.
// ---------------------------------------------------------------------------
__global__ __launch_bounds__(256) void morph_k(const float* __restrict__ x) {
    __shared__ float sP[48 * SPW];
    __shared__ float sQ[40 * SQW];
    const int tile = blockIdx.x;
    const int c    = blockIdx.y;
    const int b    = blockIdx.z;
    const int th   = tile / 6;
    const int tw   = tile - th * 6;
    const int h0   = th * 32, w0 = tw * 32;

    // stage: sP = 2^(s*x) with clamped loads + pad-select (no divergence).
    // Only cols 0..47 of each row are consumed; 48..SPW-1 are don't-care.
    const float* xm = x + (size_t)(b * C_ + c) * HW_;
    for (int idx = threadIdx.x; idx < 48 * SPW; idx += 256) {
        const int r  = idx / SPW, q = idx - r * SPW;
        const int ih = h0 - 8 + r, iw = w0 - 8 + q;
        const int ihc = min(max(ih, 0), H_ - 1);
        const int iwc = min(max(iw, 0), W_ - 1);
        const float xv = xm[ihc * W_ + iwc];
        const bool inb = (ih == ihc) && (iw == iwc);
        sP[idx] = inb ? exp2f(SCALE_IN * xv) : 1.0f;
    }
    __syncthreads();

    const int slotbase = (b * 36 + tile) * 4;
    morph_branch<1>(b, c, h0, w0, slotbase, sP, sQ);
    morph_branch<2>(b, c, h0, w0, slotbase, sP, sQ);
    morph_branch<3>(b, c, h0, w0, slotbase, sP, sQ);
    morph_branch<4>(b, c, h0, w0, slotbase, sP, sQ);
}

// ---------------------------------------------------------------------------
// finalize BN1: reduce 576 partials per channel. grid = 128
// ---------------------------------------------------------------------------
__global__ __launch_bounds__(256) void fin1_k(const float* __restrict__ gs,
                                              const float* __restrict__ bs) {
    const int chan = blockIdx.x;
    const int base = chan * 576;
    float s1 = 0.0f, s2 = 0.0f;
    for (int i = threadIdx.x; i < 576; i += 256) {
        s1 += g_p1[base + i];
        s2 += g_p1[NP1 + base + i];
    }
#pragma unroll
    for (int off = 32; off >= 1; off >>= 1) {
        s1 += __shfl_down(s1, off, 64);
        s2 += __shfl_down(s2, off, 64);
    }
    __shared__ float l1[4], l2[4];
    const int lane = threadIdx.x & 63;
    const int wv   = threadIdx.x >> 6;
    if (lane == 0) { l1[wv] = s1; l2[wv] = s2; }
    __syncthreads();
    if (threadIdx.x == 0) {
        const float S1 = l1[0] + l1[1] + l1[2] + l1[3];
        const float S2 = l2[0] + l2[1] + l2[2] + l2[3];
        const float N  = (float)(B_ * HW_);
        const float mu = S1 / N;
        const float va = fmaxf(S2 / N - mu * mu, 0.0f);
        const float sc = gs[chan] * rsqrtf(va + EPS_);
        g_stats[chan]       = sc;
        g_stats[128 + chan] = bs[chan] - mu * sc;
    }
}

// ---------------------------------------------------------------------------
// fused BN1+ReLU + 1x1 conv + BN2 partials. grid (144, 4 og, 4 b).
// Weights/scales wave-uniform (scalar loads); E bf16 bits, shift-converted.
// ---------------------------------------------------------------------------
__global__ __launch_bounds__(256) void conv_k(void) {
    const int og = blockIdx.y;
    const int b  = blockIdx.z;
    const int p  = blockIdx.x * 256 + threadIdx.x;

    float acc[8];
#pragma unroll
    for (int k = 0; k < 8; k++) acc[k] = 0.0f;

#pragma unroll 4
    for (int ci = 0; ci < 128; ci++) {
        const int br = ci >> 5;
        const int c  = ci & 31;
        const unsigned short eu = g_E[(((size_t)br * B_ + b) * C_ + c) * HW_ + p];
        float v = bf2f(eu);
        v = fmaxf(fmaf(v, g_stats[ci], g_stats[128 + ci]), 0.0f);
        const float* wr = &g_Wt[ci * 32 + og * 8];
#pragma unroll
        for (int k = 0; k < 8; k++) acc[k] = fmaf(v, wr[k], acc[k]);
    }

    float* Yp = g_Y + ((size_t)b * C_ + og * 8) * HW_ + p;
#pragma unroll
    for (int k = 0; k < 8; k++) Yp[(size_t)k * HW_] = acc[k];

    __shared__ float l1[8][4], l2[8][4];
    const int lane = threadIdx.x & 63;
    const int wv   = threadIdx.x >> 6;
#pragma unroll
    for (int k = 0; k < 8; k++) {
        float s1 = acc[k];
        float s2 = acc[k] * acc[k];
#pragma unroll
        for (int off = 32; off >= 1; off >>= 1) {
            s1 += __shfl_down(s1, off, 64);
            s2 += __shfl_down(s2, off, 64);
        }
        if (lane == 0) { l1[k][wv] = s1; l2[k][wv] = s2; }
    }
    __syncthreads();
    if (threadIdx.x < 8) {
        const int k = threadIdx.x;
        const int chan = og * 8 + k;
        const int slot = chan * (B_ * 144) + b * 144 + blockIdx.x;
        g_p2[slot]       = l1[k][0] + l1[k][1] + l1[k][2] + l1[k][3];
        g_p2[NP2 + slot] = l2[k][0] + l2[k][1] + l2[k][2] + l2[k][3];
    }
}

// ---------------------------------------------------------------------------
// finalize BN2: reduce 576 partials per channel. grid = 32
// ---------------------------------------------------------------------------
__global__ __launch_bounds__(256) void fin2_k(const float* __restrict__ g,
                                              const float* __restrict__ bb) {
    const int chan = blockIdx.x;
    const int base = chan * (B_ * 144);
    float s1 = 0.0f, s2 = 0.0f;
    for (int i = threadIdx.x; i < B_ * 144; i += 256) {
        s1 += g_p2[base + i];
        s2 += g_p2[NP2 + base + i];
    }
#pragma unroll
    for (int off = 32; off >= 1; off >>= 1) {
        s1 += __shfl_down(s1, off, 64);
        s2 += __shfl_down(s2, off, 64);
    }
    __shared__ float l1[4], l2[4];
    const int lane = threadIdx.x & 63;
    const int wv   = threadIdx.x >> 6;
    if (lane == 0) { l1[wv] = s1; l2[wv] = s2; }
    __syncthreads();
    if (threadIdx.x == 0) {
        const float S1 = l1[0] + l1[1] + l1[2] + l1[3];
        const float S2 = l2[0] + l2[1] + l2[2] + l2[3];
        const float N  = (float)(B_ * HW_);
        const float mu = S1 / N;
        const float va = fmaxf(S2 / N - mu * mu, 0.0f);
        const float sc = g[chan] * rsqrtf(va + EPS_);
        g_stats[256 + chan] = sc;
        g_stats[288 + chan] = bb[chan] - mu * sc;
    }
}

// ---------------------------------------------------------------------------
// final: BN2 + ReLU -> f32 (float4). grid (36, 32, 4)
// ---------------------------------------------------------------------------
__global__ __launch_bounds__(256) void final_k(float* __restrict__ out) {
    const int c = blockIdx.y;
    const int b = blockIdx.z;
    const size_t base = (size_t)(b * C_ + c) * HW_ + (blockIdx.x * 256 + threadIdx.x) * 4;
    const float sc = g_stats[256 + c];
    const float sh = g_stats[288 + c];
    const float4 v = *(const float4*)&g_Y[base];
    float4 r;
    r.x = fmaxf(v.x * sc + sh, 0.0f);
    r.y = fmaxf(v.y * sc + sh, 0.0f);
    r.z = fmaxf(v.z * sc + sh, 0.0f);
    r.w = fmaxf(v.w * sc + sh, 0.0f);
    *(float4*)&out[base] = r;
}

// ---------------------------------------------------------------------------
extern "C" void kernel_launch(void* const* d_in, const int* in_sizes, int n_in,
                              void* d_out, int out_size, void* d_ws, size_t ws_size,
                              hipStream_t stream) {
    const float* x  = (const float*)d_in[0];
    const float* wd = (const float*)d_in[1];
    const float* we = (const float*)d_in[2];
    const float* gs = (const float*)d_in[3];
    const float* bs = (const float*)d_in[4];
    const float* Wc = (const float*)d_in[5];
    const float* g  = (const float*)d_in[6];
    const float* bb = (const float*)d_in[7];

    prep_k<<<1, 256, 0, stream>>>(wd, we, Wc);
    morph_k<<<dim3(36, C_, B_), 256, 0, stream>>>(x);
    fin1_k<<<128, 256, 0, stream>>>(gs, bs);
    conv_k<<<dim3(HW_ / 256, 4, B_), 256, 0, stream>>>();
    fin2_k<<<32, 256, 0, stream>>>(g, bb);
    final_k<<<dim3(HW_ / 1024, C_, B_), 256, 0, stream>>>((float*)d_out);
}

// Round 12
// 101.193 us; speedup vs baseline: 1.1502x; 1.1502x over previous
//
#include <hip/hip_runtime.h>
#include <hip/hip_bf16.h>

// Problem constants
#define B_   4
#define C_   32
#define H_   192
#define W_   192
#define HW_  (H_ * W_)          // 36864
#define EPS_ 1e-5f

#define SCALE_IN  21.640425613334453f   // beta/ln2
#define SCALE_OUT 0.046209812037329687f // ln2/beta

#define SPW 48                  // sP row stride
#define SQW 40                  // sQ row stride

#define NP1 (128 * 576)         // chan * (4 b * 36 tiles * 4 waves)
#define NP2 (32 * 288)          // chan * (4 b * 72 blocks)

// bf16 <-> f32 helpers (bit-exact shift load, RNE store)
__device__ __forceinline__ float bf2f(unsigned short u) {
    return __uint_as_float((unsigned int)u << 16);
}
__device__ __forceinline__ unsigned short f2bf(float f) {
    const unsigned int u = __float_as_uint(f);
    return (unsigned short)((u + 0x7fffu + ((u >> 16) & 1u)) >> 16);
}

// ---------------------------------------------------------------------------
// Scratch (module globals; no atomics anywhere).
// ---------------------------------------------------------------------------
__device__ float          g_cw[2304];
__device__ float          g_Wt[4096];
__device__ float          g_stats[320];
__device__ float          g_p1[2 * NP1];
__device__ float          g_p2[2 * NP2];
__device__ __attribute__((aligned(16))) unsigned short g_E[(size_t)4 * B_ * C_ * HW_];  // 37.75 MB
__device__ __attribute__((aligned(16))) unsigned short g_Yb[(size_t)B_ * C_ * HW_];     // 9.44 MB

// ---------------------------------------------------------------------------
// prep: exponentiate morphology weights + transpose conv weights
// ---------------------------------------------------------------------------
__global__ void prep_k(const float* __restrict__ wd, const float* __restrict__ we,
                       const float* __restrict__ Wc) {
    for (int i = threadIdx.x; i < 2304; i += 256) {
        const float v = (i < 1152) ? wd[i] : we[i - 1152];
        g_cw[i] = exp2f(SCALE_IN * v);
    }
    for (int i = threadIdx.x; i < 4096; i += 256) {
        const int ci = i >> 5;
        const int k  = i & 31;
        g_Wt[i] = Wc[(size_t)k * 128 + ci];
    }
}

// ---------------------------------------------------------------------------
// One morphology branch (dilate-recip + erode) on a staged 48x48 P tile.
// ---------------------------------------------------------------------------
template<int D>
__device__ __forceinline__ void morph_branch(int b, int c, int h0, int w0,
                                             int slotbase,
                                             const float* __restrict__ sP,
                                             float* __restrict__ sQ) {
    constexpr int QE   = 32 + 2 * D;
    constexpr int QEG  = (QE + 3) / 4;
    constexpr int UNITS = QE * QEG;
    constexpr int POFF = 8 - 2 * D;
    constexpr int AB   = POFF & ~3;
    constexpr int OFF  = POFF & 3;
    constexpr int NR   = (OFF + 2 * D + 4 + 3) / 4;
    constexpr int NR3  = (2 * D + 4 + 3) / 4;
    constexpr int br   = D - 1;

    const int tid = threadIdx.x;
    const int cb  = (br * C_ + c) * 9;

    // ---- phase 2: Q = rcp( sum cd * P_taps ); out-of-image cells := 1 ----
    {
        float cd[9];
#pragma unroll
        for (int k = 0; k < 9; k++) cd[k] = g_cw[cb + k];

#pragma unroll
        for (int it = 0; it < 2; ++it) {
            const int unit = tid + it * 256;
            if (unit < UNITS) {
                const int qi = unit / QEG;
                const int qj = (unit - qi * QEG) * 4;
                float a0 = 0.f, a1 = 0.f, a2 = 0.f, a3 = 0.f;
#pragma unroll
                for (int i = 0; i < 3; i++) {
                    const float* rp = &sP[(qi + 8 + (i - 2) * D) * SPW + qj + AB];
                    float buf[NR * 4];
#pragma unroll
                    for (int r = 0; r < NR; r++)
                        *(float4*)&buf[r * 4] = *(const float4*)&rp[r * 4];
#pragma unroll
                    for (int j = 0; j < 3; j++) {
                        const float wgt = cd[i * 3 + j];
                        a0 = fmaf(wgt, buf[OFF + j * D + 0], a0);
                        a1 = fmaf(wgt, buf[OFF + j * D + 1], a1);
                        a2 = fmaf(wgt, buf[OFF + j * D + 2], a2);
                        a3 = fmaf(wgt, buf[OFF + j * D + 3], a3);
                    }
                }
                float q0 = __builtin_amdgcn_rcpf(a0);
                float q1 = __builtin_amdgcn_rcpf(a1);
                float q2 = __builtin_amdgcn_rcpf(a2);
                float q3 = __builtin_amdgcn_rcpf(a3);
                const int hq = h0 - D + qi;
                const int wq = w0 - D + qj;
                const bool rowo = (hq < 0) || (hq >= H_);
                q0 = (rowo || (wq + 0 < 0) || (wq + 0 >= W_)) ? 1.0f : q0;
                q1 = (rowo || (wq + 1 < 0) || (wq + 1 >= W_)) ? 1.0f : q1;
                q2 = (rowo || (wq + 2 < 0) || (wq + 2 >= W_)) ? 1.0f : q2;
                q3 = (rowo || (wq + 3 < 0) || (wq + 3 >= W_)) ? 1.0f : q3;
                *(float4*)&sQ[qi * SQW + qj] = make_float4(q0, q1, q2, q3);
            }
        }
    }
    __syncthreads();

    // ---- phase 3: E = -(ln2/beta)*log2( sum ce * Q_taps ), 4 px/thread ----
    {
        float ce[9];
#pragma unroll
        for (int k = 0; k < 9; k++) ce[k] = g_cw[1152 + cb + k];

        const int oi = tid >> 3;
        const int oj = (tid & 7) * 4;
        float t0 = 0.f, t1 = 0.f, t2 = 0.f, t3 = 0.f;
#pragma unroll
        for (int i = 0; i < 3; i++) {
            const float* rq = &sQ[(oi + i * D) * SQW + oj];
            float buf[NR3 * 4];
#pragma unroll
            for (int r = 0; r < NR3; r++)
                *(float4*)&buf[r * 4] = *(const float4*)&rq[r * 4];
#pragma unroll
            for (int j = 0; j < 3; j++) {
                const float wgt = ce[i * 3 + j];
                t0 = fmaf(wgt, buf[j * D + 0], t0);
                t1 = fmaf(wgt, buf[j * D + 1], t1);
                t2 = fmaf(wgt, buf[j * D + 2], t2);
                t3 = fmaf(wgt, buf[j * D + 3], t3);
            }
        }
        const float e0 = -SCALE_OUT * log2f(t0);
        const float e1 = -SCALE_OUT * log2f(t1);
        const float e2 = -SCALE_OUT * log2f(t2);
        const float e3 = -SCALE_OUT * log2f(t3);

        ushort4 r4;
        r4.x = f2bf(e0); r4.y = f2bf(e1); r4.z = f2bf(e2); r4.w = f2bf(e3);
        *(ushort4*)&g_E[(((size_t)br * B_ + b) * C_ + c) * HW_
                        + (size_t)(h0 + oi) * W_ + w0 + oj] = r4;

        float s1 = e0 + e1 + e2 + e3;
        float s2 = e0 * e0 + e1 * e1 + e2 * e2 + e3 * e3;
#pragma unroll
        for (int off = 32; off >= 1; off >>= 1) {
            s1 += __shfl_down(s1, off, 64);
            s2 += __shfl_down(s2, off, 64);
        }
        if ((tid & 63) == 0) {
            const int slot = (br * C_ + c) * 576 + slotbase + (tid >> 6);
            g_p1[slot]       = s1;
            g_p1[NP1 + slot] = s2;
        }
    }
    __syncthreads();
}

// ---------------------------------------------------------------------------
// fused all-branch morphology. grid (36 tiles, 32 c, 4 b), 256 threads.
// ---------------------------------------------------------------------------
__global__ __launch_bounds__(256) void morph_k(const float* __restrict__ x) {
    __shared__ float sP[48 * SPW];
    __shared__ float sQ[40 * SQW];
    const int tile = blockIdx.x;
    const int c    = blockIdx.y;
    const int b    = blockIdx.z;
    const int th   = tile / 6;
    const int tw   = tile - th * 6;
    const int h0   = th * 32, w0 = tw * 32;

    const float* xm = x + (size_t)(b * C_ + c) * HW_;
    for (int idx = threadIdx.x; idx < 48 * 48; idx += 256) {
        const int r  = idx / 48, q = idx - r * 48;
        const int ih = h0 - 8 + r, iw = w0 - 8 + q;
        const int ihc = min(max(ih, 0), H_ - 1);
        const int iwc = min(max(iw, 0), W_ - 1);
        const float xv = xm[ihc * W_ + iwc];
        const bool inb = (ih == ihc) && (iw == iwc);
        sP[r * SPW + q] = inb ? exp2f(SCALE_IN * xv) : 1.0f;
    }
    __syncthreads();

    const int slotbase = (b * 36 + tile) * 4;
    morph_branch<1>(b, c, h0, w0, slotbase, sP, sQ);
    morph_branch<2>(b, c, h0, w0, slotbase, sP, sQ);
    morph_branch<3>(b, c, h0, w0, slotbase, sP, sQ);
    morph_branch<4>(b, c, h0, w0, slotbase, sP, sQ);
}

// ---------------------------------------------------------------------------
// finalize BN1: reduce 576 partials per channel. grid = 128
// ---------------------------------------------------------------------------
__global__ __launch_bounds__(256) void fin1_k(const float* __restrict__ gs,
                                              const float* __restrict__ bs) {
    const int chan = blockIdx.x;
    const int base = chan * 576;
    float s1 = 0.0f, s2 = 0.0f;
    for (int i = threadIdx.x; i < 576; i += 256) {
        s1 += g_p1[base + i];
        s2 += g_p1[NP1 + base + i];
    }
#pragma unroll
    for (int off = 32; off >= 1; off >>= 1) {
        s1 += __shfl_down(s1, off, 64);
        s2 += __shfl_down(s2, off, 64);
    }
    __shared__ float l1[4], l2[4];
    const int lane = threadIdx.x & 63;
    const int wv   = threadIdx.x >> 6;
    if (lane == 0) { l1[wv] = s1; l2[wv] = s2; }
    __syncthreads();
    if (threadIdx.x == 0) {
        const float S1 = l1[0] + l1[1] + l1[2] + l1[3];
        const float S2 = l2[0] + l2[1] + l2[2] + l2[3];
        const float N  = (float)(B_ * HW_);
        const float mu = S1 / N;
        const float va = fmaxf(S2 / N - mu * mu, 0.0f);
        const float sc = gs[chan] * rsqrtf(va + EPS_);
        g_stats[chan]       = sc;
        g_stats[128 + chan] = bs[chan] - mu * sc;
    }
}

// ---------------------------------------------------------------------------
// fused BN1+ReLU + 1x1 conv + BN2 partials. grid (72, 4 og, 4 b).
// 2 pixels/thread: one 4B uint load = 2 bf16 E values per ci.
// Weights/scales wave-uniform (scalar); Y stored bf16 (stats from f32 accs).
// ---------------------------------------------------------------------------
__global__ __launch_bounds__(256) void conv_k(void) {
    const int og = blockIdx.y;
    const int b  = blockIdx.z;
    const int p  = (blockIdx.x * 256 + threadIdx.x) * 2;

    float acc0[8], acc1[8];
#pragma unroll
    for (int k = 0; k < 8; k++) { acc0[k] = 0.0f; acc1[k] = 0.0f; }

#pragma unroll 8
    for (int ci = 0; ci < 128; ci++) {
        const int br = ci >> 5;
        const int c  = ci & 31;
        const unsigned int eu =
            *(const unsigned int*)&g_E[(((size_t)br * B_ + b) * C_ + c) * HW_ + p];
        float v0 = __uint_as_float(eu << 16);
        float v1 = __uint_as_float(eu & 0xffff0000u);
        const float sc = g_stats[ci], sh = g_stats[128 + ci];
        v0 = fmaxf(fmaf(v0, sc, sh), 0.0f);
        v1 = fmaxf(fmaf(v1, sc, sh), 0.0f);
        const float* wr = &g_Wt[ci * 32 + og * 8];
#pragma unroll
        for (int k = 0; k < 8; k++) {
            acc0[k] = fmaf(v0, wr[k], acc0[k]);
            acc1[k] = fmaf(v1, wr[k], acc1[k]);
        }
    }

    unsigned short* Yp = g_Yb + ((size_t)b * C_ + og * 8) * HW_ + p;
#pragma unroll
    for (int k = 0; k < 8; k++) {
        const unsigned int pack =
            (unsigned int)f2bf(acc0[k]) | ((unsigned int)f2bf(acc1[k]) << 16);
        *(unsigned int*)&Yp[(size_t)k * HW_] = pack;
    }

    // BN2 block partials for the 8 channels (computed from unrounded accs)
    __shared__ float l1[8][4], l2[8][4];
    const int lane = threadIdx.x & 63;
    const int wv   = threadIdx.x >> 6;
#pragma unroll
    for (int k = 0; k < 8; k++) {
        float s1 = acc0[k] + acc1[k];
        float s2 = acc0[k] * acc0[k] + acc1[k] * acc1[k];
#pragma unroll
        for (int off = 32; off >= 1; off >>= 1) {
            s1 += __shfl_down(s1, off, 64);
            s2 += __shfl_down(s2, off, 64);
        }
        if (lane == 0) { l1[k][wv] = s1; l2[k][wv] = s2; }
    }
    __syncthreads();
    if (threadIdx.x < 8) {
        const int k = threadIdx.x;
        const int chan = og * 8 + k;
        const int slot = chan * 288 + b * 72 + blockIdx.x;
        g_p2[slot]       = l1[k][0] + l1[k][1] + l1[k][2] + l1[k][3];
        g_p2[NP2 + slot] = l2[k][0] + l2[k][1] + l2[k][2] + l2[k][3];
    }
}

// ---------------------------------------------------------------------------
// finalize BN2: reduce 288 partials per channel. grid = 32
// ---------------------------------------------------------------------------
__global__ __launch_bounds__(256) void fin2_k(const float* __restrict__ g,
                                              const float* __restrict__ bb) {
    const int chan = blockIdx.x;
    const int base = chan * 288;
    float s1 = 0.0f, s2 = 0.0f;
    for (int i = threadIdx.x; i < 288; i += 256) {
        s1 += g_p2[base + i];
        s2 += g_p2[NP2 + base + i];
    }
#pragma unroll
    for (int off = 32; off >= 1; off >>= 1) {
        s1 += __shfl_down(s1, off, 64);
        s2 += __shfl_down(s2, off, 64);
    }
    __shared__ float l1[4], l2[4];
    const int lane = threadIdx.x & 63;
    const int wv   = threadIdx.x >> 6;
    if (lane == 0) { l1[wv] = s1; l2[wv] = s2; }
    __syncthreads();
    if (threadIdx.x == 0) {
        const float S1 = l1[0] + l1[1] + l1[2] + l1[3];
        const float S2 = l2[0] + l2[1] + l2[2] + l2[3];
        const float N  = (float)(B_ * HW_);
        const float mu = S1 / N;
        const float va = fmaxf(S2 / N - mu * mu, 0.0f);
        const float sc = g[chan] * rsqrtf(va + EPS_);
        g_stats[256 + chan] = sc;
        g_stats[288 + chan] = bb[chan] - mu * sc;
    }
}

// ---------------------------------------------------------------------------
// final: BN2 + ReLU -> f32. 8 px/thread (uint4 = 8 bf16). grid (18, 32, 4)
// ---------------------------------------------------------------------------
__global__ __launch_bounds__(256) void final_k(float* __restrict__ out) {
    const int c = blockIdx.y;
    const int b = blockIdx.z;
    const size_t base = (size_t)(b * C_ + c) * HW_ + (blockIdx.x * 256 + threadIdx.x) * 8;
    const float sc = g_stats[256 + c];
    const float sh = g_stats[288 + c];
    const uint4 u = *(const uint4*)&g_Yb[base];

    float4 r0, r1;
    r0.x = fmaxf(fmaf(__uint_as_float(u.x << 16),        sc, sh), 0.0f);
    r0.y = fmaxf(fmaf(__uint_as_float(u.x & 0xffff0000u), sc, sh), 0.0f);
    r0.z = fmaxf(fmaf(__uint_as_float(u.y << 16),        sc, sh), 0.0f);
    r0.w = fmaxf(fmaf(__uint_as_float(u.y & 0xffff0000u), sc, sh), 0.0f);
    r1.x = fmaxf(fmaf(__uint_as_float(u.z << 16),        sc, sh), 0.0f);
    r1.y = fmaxf(fmaf(__uint_as_float(u.z & 0xffff0000u), sc, sh), 0.0f);
    r1.z = fmaxf(fmaf(__uint_as_float(u.w << 16),        sc, sh), 0.0f);
    r1.w = fmaxf(fmaf(__uint_as_float(u.w & 0xffff0000u), sc, sh), 0.0f);

    *(float4*)&out[base]     = r0;
    *(float4*)&out[base + 4] = r1;
}

// ---------------------------------------------------------------------------
extern "C" void kernel_launch(void* const* d_in, const int* in_sizes, int n_in,
                              void* d_out, int out_size, void* d_ws, size_t ws_size,
                              hipStream_t stream) {
    const float* x  = (const float*)d_in[0];
    const float* wd = (const float*)d_in[1];
    const float* we = (const float*)d_in[2];
    const float* gs = (const float*)d_in[3];
    const float* bs = (const float*)d_in[4];
    const float* Wc = (const float*)d_in[5];
    const float* g  = (const float*)d_in[6];
    const float* bb = (const float*)d_in[7];

    prep_k<<<1, 256, 0, stream>>>(wd, we, Wc);
    morph_k<<<dim3(36, C_, B_), 256, 0, stream>>>(x);
    fin1_k<<<128, 256, 0, stream>>>(gs, bs);
    conv_k<<<dim3(HW_ / 512, 4, B_), 256, 0, stream>>>();
    fin2_k<<<32, 256, 0, stream>>>(g, bb);
    final_k<<<dim3(HW_ / 2048, C_, B_), 256, 0, stream>>>((float*)d_out);
}